// Round 12
// baseline (140.675 us; speedup 1.0000x reference)
//
#include <hip/hip_runtime.h>

// NonImagingRod: per-ray damped-Newton (LM) root find on f(t) = A t^2 + B t + C.
// Round-12: R8's proven 2-chunk pipeline skeleton; ONLY change = LM loop fully
// unrolled (31 straight-line groups). Rationale: R8-R11 pin at ~52 cyc per
// wave-ray-iter (floor ~20) across op-count/op-mix/pipeline-depth/packing/
// source-order changes; the remaining source-reachable overhead is the loop
// back-edge: ~3 SALU per 28 VALU AND a scheduling barrier preventing
// cross-iteration interleave of different rays' chains. Full unroll removes
// both (live set unchanged ~30 regs; ~14 KB I-footprint fits I-cache).
//
// Codegen notes (hard-won):
//  - 8 SIMULTANEOUSLY-iterated rays: spill wall (R2-5). 4 iterated + 24
//    prefetch regs is proven clean (R8: VGPR 32, FETCH stable 49.2 MB).
//  - No-spill signature: FETCH_SIZE stable ~49-50 MB.
//  - v_pk_* neutral on CDNA4 (R10); source statement order irrelevant (R11);
//    pipeline depth 2 suffices (R9); rcp vs Newton-from-magic neutral (R7).
//  - Clamp(+-1000) provably inactive; rcp ~1ulp fine (absmax 0.0, R2-R11).

#define LM_ITERS 31
constexpr float DAMPING = 0.5f;

__global__ __launch_bounds__(256) void rod_kernel(
    const float* __restrict__ P, const float* __restrict__ V,
    const float* __restrict__ Rm, const float* __restrict__ Tv,
    const float* __restrict__ c_ptr, double* __restrict__ ws, int n)
{
    const float c  = c_ptr[0];
    const float r00 = Rm[0], r01 = Rm[1], r02 = Rm[2];
    const float r10 = Rm[3], r11 = Rm[4], r12 = Rm[5];
    const float r20 = Rm[6], r21 = Rm[7], r22 = Rm[8];
    const float t0 = Tv[0], t1 = Tv[1], t2 = Tv[2];

    const int tid      = blockIdx.x * blockDim.x + threadIdx.x;
    const int nthreads = gridDim.x * blockDim.x;
    const int g0 = tid;                 // chunk 0: rays [4*g0, 4*g0+4)
    const int g1 = tid + nthreads;      // chunk 1: rays [4*g1, 4*g1+4)

    const float4* P4 = (const float4*)P;
    const float4* V4 = (const float4*)V;

    double acc = 0.0;

    float nA[4], f[4], fp[4];
    auto setup4 = [&](const float4& qa, const float4& qb, const float4& qc,
                      const float4& ua, const float4& ub, const float4& uc) {
        const float px[4] = {qa.x, qa.w, qb.z, qc.y};
        const float py[4] = {qa.y, qb.x, qb.w, qc.z};
        const float pz[4] = {qa.z, qb.y, qc.x, qc.w};
        const float wx[4] = {ua.x, ua.w, ub.z, uc.y};
        const float wy[4] = {ua.y, ub.x, ub.w, uc.z};
        const float wz[4] = {ua.z, ub.y, uc.x, uc.w};
        #pragma unroll
        for (int r = 0; r < 4; ++r) {
            const float qx = px[r] - t0, qy = py[r] - t1, qz = pz[r] - t2;
            const float plx = qx * r00 + qy * r10 + qz * r20;
            const float ply = qx * r01 + qy * r11 + qz * r21;
            const float plz = qx * r02 + qy * r12 + qz * r22;
            const float vlx = wx[r] * r00 + wy[r] * r10 + wz[r] * r20;
            const float vly = wx[r] * r01 + wy[r] * r11 + wz[r] * r21;
            const float vlz = wx[r] * r02 + wy[r] * r12 + wz[r] * r22;
            nA[r] = c * (vly * vly + vlz * vlz);                 // -A
            f[r]  = plx - c * (ply * ply + plz * plz);           // f(0)  = C
            fp[r] = vlx - 2.0f * c * (ply * vly + plz * vlz);    // f'(0) = B
        }
    };

    // LM step (exact quadratic Taylor update):
    //   den = fp^2 + damping; d = (f*fp)*rcp(den);
    //   tmp = fp - A*d; f <- f - d*tmp; fp <- tmp - A*d.
    // FULLY UNROLLED: no back-edge -> no per-iter SALU, and the scheduler can
    // software-pipeline ray r's iter k+1 against ray r' iter k.
    auto iterate = [&]() {
        #pragma unroll
        for (int it = 0; it < LM_ITERS; ++it) {
            #pragma unroll
            for (int r = 0; r < 4; ++r) {
                const float den = fmaf(fp[r], fp[r], DAMPING);
                const float rcp = __builtin_amdgcn_rcpf(den);  // ~1 ulp; LM self-corrects
                const float d   = (f[r] * fp[r]) * rcp;
                const float tmp = fmaf(nA[r], d, fp[r]);
                f[r]  = fmaf(-d, tmp, f[r]);
                fp[r] = fmaf(nA[r], d, tmp);
            }
        }
    };

    auto accum = [&](int g) {
        if (4 * g + 4 <= n) {
            acc += (double)f[0] * (double)f[0] + (double)f[1] * (double)f[1];
            acc += (double)f[2] * (double)f[2] + (double)f[3] * (double)f[3];
        } else {
            for (int r = 0; r < 4; ++r)
                if (4 * g + r < n) acc += (double)f[r] * (double)f[r];
        }
    };

    // ---- chunk 0 load ----
    float4 a0{}, b0{}, c0{}, u0{}, v0{}, w0{};
    if (4 * g0 < n) {
        a0 = P4[g0 * 3 + 0]; b0 = P4[g0 * 3 + 1]; c0 = P4[g0 * 3 + 2];
        u0 = V4[g0 * 3 + 0]; v0 = V4[g0 * 3 + 1]; w0 = V4[g0 * 3 + 2];
    }
    setup4(a0, b0, c0, u0, v0, w0);

    // ---- prefetch chunk 1 (independent: overlaps chunk-0 loop) ----
    float4 a1{}, b1{}, c1{}, u1{}, v1{}, w1{};
    const bool has1 = (4 * g1 < n);
    if (has1) {
        a1 = P4[g1 * 3 + 0]; b1 = P4[g1 * 3 + 1]; c1 = P4[g1 * 3 + 2];
        u1 = V4[g1 * 3 + 0]; v1 = V4[g1 * 3 + 1]; w1 = V4[g1 * 3 + 2];
    }

    iterate();                           // chunk 0
    if (4 * g0 < n) accum(g0);

    setup4(a1, b1, c1, u1, v1, w1);
    iterate();                           // chunk 1
    if (has1) accum(g1);

    // wave(64) shuffle reduce -> LDS across 4 waves -> one f64 atomic per block
    for (int off = 32; off > 0; off >>= 1)
        acc += __shfl_down(acc, off, 64);
    __shared__ double sacc[4];
    const int lane = threadIdx.x & 63, wave = threadIdx.x >> 6;
    if (lane == 0) sacc[wave] = acc;
    __syncthreads();
    if (threadIdx.x == 0) {
        atomicAdd(ws, sacc[0] + sacc[1] + sacc[2] + sacc[3]);
    }
}

__global__ void rod_finalize(const double* __restrict__ ws,
                             const float* __restrict__ loss_in,
                             float* __restrict__ out, double inv_n)
{
    out[0] = (float)(ws[0] * inv_n + (double)loss_in[0]);
}

extern "C" void kernel_launch(void* const* d_in, const int* in_sizes, int n_in,
                              void* d_out, int out_size, void* d_ws, size_t ws_size,
                              hipStream_t stream) {
    const float* P       = (const float*)d_in[0];
    const float* V       = (const float*)d_in[1];
    const float* R       = (const float*)d_in[2];
    const float* T       = (const float*)d_in[3];
    const float* c       = (const float*)d_in[4];
    const float* loss_in = (const float*)d_in[5];

    const int n = in_sizes[0] / 3;           // number of rays

    // d_ws is poisoned to 0xAA before every launch — zero the accumulator.
    hipMemsetAsync(d_ws, 0, sizeof(double), stream);

    // 8 rays/thread as 2 pipelined 4-ray chunks (R8's proven grid: 2048 blocks).
    const int threads = (n + 7) / 8;
    const int block   = 256;
    const int grid    = (threads + block - 1) / block;
    rod_kernel<<<grid, block, 0, stream>>>(P, V, R, T, c, (double*)d_ws, n);
    rod_finalize<<<1, 1, 0, stream>>>((const double*)d_ws, loss_in,
                                      (float*)d_out, 1.0 / (double)n);
}